// Round 16
// baseline (154.713 us; speedup 1.0000x reference)
//
#include <hip/hip_runtime.h>
#include <math.h>

#define TB 2048
#define TK 128
#define TD 512
#define BR 8                 // real rows per block (MFMA M=16, rows 8..15 zero)
#define NBLK (TB / BR)       // 256 blocks per replica
#define NKS 32               // K' = 1024 = 32 MFMA k-steps of 32
#define SLICEW ((size_t)TK * 2 * TD)       // Wfrag elems per replica (256 KB)
#define OUTSZ ((size_t)TB * TK + TB)       // output elems per replica

typedef _Float16 half8 __attribute__((ext_vector_type(8)));
typedef float f32x4 __attribute__((ext_vector_type(4)));

// DIAGNOSTIC ROUND (REP=32): R15's kernels replicated with private param/out
// slices so both surface above the 40us poison fills with true counters.
// Replica 0 of gmm writes the real output; others write private ws slices.

// ---------------------------------------------------------------------------
__global__ __launch_bounds__(128) void prep_kernel(const float* __restrict__ C,
        const float* __restrict__ Dm, _Float16* __restrict__ Wfrag,
        float* __restrict__ off, float* __restrict__ ebuf, int nk) {
    __shared__ float sE[2], sL[2];
    const int k = blockIdx.x % nk;
    const int rep = blockIdx.x / nk;
    const int t = threadIdx.x;
    const int ks = t >> 2, lg = t & 3;
    const int d0 = ks * 16 + lg * 4;

    _Float16* wf = Wfrag + (size_t)rep * SLICEW;

    float4 dv = *reinterpret_cast<const float4*>(&Dm[(size_t)k * TD + d0]);
    float4 cv = *reinterpret_cast<const float4*>(&C[(size_t)k * TD + d0]);
    float a0 = fabsf(dv.x) + 1e-8f, a1 = fabsf(dv.y) + 1e-8f;
    float a2 = fabsf(dv.z) + 1e-8f, a3 = fabsf(dv.w) + 1e-8f;
    float i0 = 1.f / a0, i1 = 1.f / a1, i2 = 1.f / a2, i3 = 1.f / a3;
    float c0 = cv.x * i0, c1 = cv.y * i1, c2 = cv.z * i2, c3 = cv.w * i3;

    half8 h;
    h[0] = (_Float16)i0; h[1] = (_Float16)(-2.f * c0);
    h[2] = (_Float16)i1; h[3] = (_Float16)(-2.f * c1);
    h[4] = (_Float16)i2; h[5] = (_Float16)(-2.f * c2);
    h[6] = (_Float16)i3; h[7] = (_Float16)(-2.f * c3);
    *reinterpret_cast<half8*>(
        &wf[(((size_t)(k >> 4) * NKS + ks) * 64 + lg * 16 + (k & 15)) * 8]) = h;

    float es = (cv.x * c0 + cv.y * c1) + (cv.z * c2 + cv.w * c3);
    float ls = logf((a0 * a1) * (a2 * a3));
    #pragma unroll
    for (int m = 1; m <= 32; m <<= 1) {
        es += __shfl_xor(es, m, 64);
        ls += __shfl_xor(ls, m, 64);
    }
    if ((t & 63) == 0) { sE[t >> 6] = es; sL[t >> 6] = ls; }
    __syncthreads();
    if (t == 0) {
        float E = sE[0] + sE[1], L = sL[0] + sL[1];
        off[rep * TK + k] = -0.5f * (E + L);
        ebuf[rep * TK + k] = E;
    }
}

// ---------------------------------------------------------------------------
__global__ __launch_bounds__(512) void gmm_kernel(const float* __restrict__ x,
        const _Float16* __restrict__ Wfrag, const float* __restrict__ off,
        const float* __restrict__ ebuf, float* __restrict__ out,
        float* __restrict__ wsout, int nblk) {
    __shared__ __align__(16) _Float16 XAf[NKS * 64 * 8];   // 32 KB
    __shared__ float red_m[8][BR], red_s[8][BR], red_g[8][BR];
    __shared__ int   red_i[8][BR];

    const int tid = threadIdx.x;
    const int rep = blockIdx.x / nblk;
    const int ib = blockIdx.x % nblk;
    const int l = tid & 63;
    const int w = tid >> 6;
    const int l15 = l & 15;
    const int lg = l >> 4;
    const int b0 = ib * BR;
    const int col = w * 16 + l15;

    float* op = (rep == 0) ? out : (wsout + (size_t)(rep - 1) * OUTSZ);
    const _Float16* wbase = Wfrag + (size_t)rep * SLICEW;
    const float* offr = off + rep * TK;
    const float* ebr = ebuf + rep * TK;

    #pragma unroll
    for (int i = 0; i < 4; ++i) {
        int rec = tid + i * 512;
        int ks = rec >> 6;
        int lr = rec & 63;
        int row = lr & 15;
        int lgr = lr >> 4;
        half8 h = (half8){0, 0, 0, 0, 0, 0, 0, 0};
        if (row < BR) {
            int d0 = ks * 16 + lgr * 4;
            float4 v = *reinterpret_cast<const float4*>(
                &x[(size_t)(b0 + row) * TD + d0]);
            h[0] = (_Float16)(v.x * v.x); h[1] = (_Float16)v.x;
            h[2] = (_Float16)(v.y * v.y); h[3] = (_Float16)v.y;
            h[4] = (_Float16)(v.z * v.z); h[5] = (_Float16)v.z;
            h[6] = (_Float16)(v.w * v.w); h[7] = (_Float16)v.w;
        }
        *reinterpret_cast<half8*>(&XAf[(size_t)rec * 8]) = h;
    }
    __syncthreads();

    const _Float16* wf = wbase + (size_t)w * NKS * 64 * 8;
    f32x4 acc0 = (f32x4){0.f, 0.f, 0.f, 0.f};
    f32x4 acc1 = (f32x4){0.f, 0.f, 0.f, 0.f};
    #pragma unroll 8
    for (int ks = 0; ks < NKS; ks += 2) {
        half8 bv0 = *reinterpret_cast<const half8*>(&wf[((size_t)ks * 64 + l) * 8]);
        half8 av0 = *reinterpret_cast<const half8*>(&XAf[((size_t)ks * 64 + l) * 8]);
        half8 bv1 = *reinterpret_cast<const half8*>(&wf[((size_t)(ks + 1) * 64 + l) * 8]);
        half8 av1 = *reinterpret_cast<const half8*>(&XAf[((size_t)(ks + 1) * 64 + l) * 8]);
        acc0 = __builtin_amdgcn_mfma_f32_16x16x32_f16(av0, bv0, acc0, 0, 0, 0);
        acc1 = __builtin_amdgcn_mfma_f32_16x16x32_f16(av1, bv1, acc1, 0, 0, 0);
    }
    f32x4 acc = acc0 + acc1;

    const float offc = offr[col];
    float sv[4], bv[4], bg[4], ps[4];
    int bi[4];
    #pragma unroll
    for (int e = 0; e < 4; ++e) {
        sv[e] = fmaf(-0.5f, acc[e], offc);
        bv[e] = sv[e]; bi[e] = col; bg[e] = acc[e];
    }
    #pragma unroll
    for (int msk = 1; msk <= 8; msk <<= 1) {
        #pragma unroll
        for (int e = 0; e < 4; ++e) {
            float ov = __shfl_xor(bv[e], msk, 64);
            int   oi = __shfl_xor(bi[e], msk, 64);
            float og = __shfl_xor(bg[e], msk, 64);
            if (ov > bv[e] || (ov == bv[e] && oi < bi[e])) {
                bv[e] = ov; bi[e] = oi; bg[e] = og;
            }
        }
    }
    #pragma unroll
    for (int e = 0; e < 4; ++e) ps[e] = expf(sv[e] - bv[e]);
    #pragma unroll
    for (int msk = 1; msk <= 8; msk <<= 1)
        #pragma unroll
        for (int e = 0; e < 4; ++e) ps[e] += __shfl_xor(ps[e], msk, 64);

    if (l15 == 0) {
        #pragma unroll
        for (int e = 0; e < 4; ++e) {
            int r = lg * 4 + e;
            if (r < BR) {
                red_m[w][r] = bv[e];
                red_s[w][r] = ps[e];
                red_i[w][r] = bi[e];
                red_g[w][r] = bg[e];
            }
        }
    }
    __syncthreads();

    const float LOGC = -18.420680743952367f;  // ln(1e-8)
    #pragma unroll
    for (int e = 0; e < 4; ++e) {
        int r = lg * 4 + e;
        if (r < BR) {
            float M = red_m[0][r];
            #pragma unroll
            for (int w2 = 1; w2 < 8; ++w2) M = fmaxf(M, red_m[w2][r]);
            float S = 0.f;
            #pragma unroll
            for (int w2 = 0; w2 < 8; ++w2) S += red_s[w2][r] * expf(red_m[w2][r] - M);
            float lse = logf(S) + M;
            op[(size_t)(b0 + r) * TK + col] = fmaxf(sv[e] - lse, LOGC);
        }
    }

    if (w == 0 && l15 == 0) {
        #pragma unroll
        for (int e = 0; e < 4; ++e) {
            int r = lg * 4 + e;
            if (r < BR) {
                float v = red_m[0][r]; int ki = red_i[0][r]; float g = red_g[0][r];
                #pragma unroll
                for (int w2 = 1; w2 < 8; ++w2) {
                    float v2 = red_m[w2][r]; int i2 = red_i[w2][r];
                    if (v2 > v || (v2 == v && i2 < ki)) { v = v2; ki = i2; g = red_g[w2][r]; }
                }
                op[(size_t)TB * TK + b0 + r] = sqrtf(fmaxf(g + ebr[ki], 0.f));
            }
        }
    }
}

// ---------------------------------------------------------------------------
extern "C" void kernel_launch(void* const* d_in, const int* in_sizes, int n_in,
                              void* d_out, int out_size, void* d_ws, size_t ws_size,
                              hipStream_t stream) {
    const float* x  = (const float*)d_in[0];
    const float* C  = (const float*)d_in[1];
    const float* Dm = (const float*)d_in[2];
    float* out = (float*)d_out;

    // need: REP*(Wfrag 256KB) + REP*1KB off/ebuf + (REP-1)*OUTSZ*4
    const size_t needRep = 32 * SLICEW * sizeof(_Float16) + 32 * 2 * TK * sizeof(float)
                         + 31 * OUTSZ * sizeof(float) + 4096;
    const int REP = (ws_size >= needRep) ? 32 : 1;

    _Float16* Wfrag = (_Float16*)d_ws;
    float* off   = (float*)((char*)d_ws + (size_t)REP * SLICEW * sizeof(_Float16));
    float* ebuf  = off + (size_t)REP * TK;
    float* wsout = ebuf + (size_t)REP * TK;

    prep_kernel<<<TK * REP, 128, 0, stream>>>(C, Dm, Wfrag, off, ebuf, TK);
    gmm_kernel<<<NBLK * REP, 512, 0, stream>>>(x, Wfrag, off, ebuf, out, wsout, NBLK);
}

// Round 17
// 21.711 us; speedup vs baseline: 7.1262x; 7.1262x over previous
//
#include <hip/hip_runtime.h>
#include <math.h>

#define TB 2048
#define TK 128
#define TD 512
#define BR 8                 // real rows per block (MFMA M=16, rows 8..15 zero)
#define NBLK (TB / BR)       // 256 blocks = 1 per CU
#define NKS 32               // K' = 1024 = 32 MFMA k-steps of 32

typedef _Float16 half8 __attribute__((ext_vector_type(8)));
typedef float f32x4 __attribute__((ext_vector_type(4)));

// k' mapping (both operands): k' = 2*d + t ; t=0 -> A:x^2, B:1/a ; t=1 -> A:x, B:-2c/a
// Fragment record (ks, lane): col/row = lane&15, d0 = ks*16 + (lane>>4)*4
// ws: Wfrag f16[8 cb][32 ks][64 lane][8] = 256 KB ; off f32[128] ; ebuf f32[128]

// ---------------------------------------------------------------------------
__global__ __launch_bounds__(128) void prep_kernel(const float* __restrict__ C,
        const float* __restrict__ Dm, _Float16* __restrict__ Wfrag,
        float* __restrict__ off, float* __restrict__ ebuf) {
    __shared__ float sE[2], sL[2];
    const int k = blockIdx.x;
    const int t = threadIdx.x;
    const int ks = t >> 2, lg = t & 3;
    const int d0 = ks * 16 + lg * 4;

    float4 dv = *reinterpret_cast<const float4*>(&Dm[(size_t)k * TD + d0]);
    float4 cv = *reinterpret_cast<const float4*>(&C[(size_t)k * TD + d0]);
    float a0 = fabsf(dv.x) + 1e-8f, a1 = fabsf(dv.y) + 1e-8f;
    float a2 = fabsf(dv.z) + 1e-8f, a3 = fabsf(dv.w) + 1e-8f;
    float i0 = 1.f / a0, i1 = 1.f / a1, i2 = 1.f / a2, i3 = 1.f / a3;
    float c0 = cv.x * i0, c1 = cv.y * i1, c2 = cv.z * i2, c3 = cv.w * i3;

    half8 h;
    h[0] = (_Float16)i0; h[1] = (_Float16)(-2.f * c0);
    h[2] = (_Float16)i1; h[3] = (_Float16)(-2.f * c1);
    h[4] = (_Float16)i2; h[5] = (_Float16)(-2.f * c2);
    h[6] = (_Float16)i3; h[7] = (_Float16)(-2.f * c3);
    *reinterpret_cast<half8*>(
        &Wfrag[(((size_t)(k >> 4) * NKS + ks) * 64 + lg * 16 + (k & 15)) * 8]) = h;

    float es = (cv.x * c0 + cv.y * c1) + (cv.z * c2 + cv.w * c3);
    float ls = logf((a0 * a1) * (a2 * a3));   // a in [0.9,1.1]: product safe
    #pragma unroll
    for (int m = 1; m <= 32; m <<= 1) {
        es += __shfl_xor(es, m, 64);
        ls += __shfl_xor(ls, m, 64);
    }
    if ((t & 63) == 0) { sE[t >> 6] = es; sL[t >> 6] = ls; }
    __syncthreads();
    if (t == 0) {
        float E = sE[0] + sE[1], L = sL[0] + sL[1];
        off[k] = -0.5f * (E + L);
        ebuf[k] = E;
    }
}

// ---------------------------------------------------------------------------
// main: 256 blocks x 1024 thr (16 waves = 4 waves/SIMD). Block = 8 rows x
// 128 cols, K' split in half across wave pairs: wave (kh, wc) does 16 MFMA of
// K'-half kh for col-group wc. acc halves combined through LDS; epilogue on
// the 8 kh==0 waves.
// ---------------------------------------------------------------------------
__global__ __launch_bounds__(1024) void gmm_kernel(const float* __restrict__ x,
        const _Float16* __restrict__ Wfrag, const float* __restrict__ off,
        const float* __restrict__ ebuf, float* __restrict__ out) {
    __shared__ __align__(16) _Float16 XAf[NKS * 64 * 8];   // 32 KB, fragment order
    __shared__ __align__(16) float accX[8][64][4];         // 8 KB
    __shared__ float red_m[8][BR], red_s[8][BR], red_g[8][BR];
    __shared__ int   red_i[8][BR];

    const int tid = threadIdx.x;
    const int l = tid & 63;
    const int w = tid >> 6;       // 0..15
    const int kh = w >> 3;        // K'-half
    const int wc = w & 7;         // col-group
    const int l15 = l & 15;
    const int lg = l >> 4;
    const int b0 = blockIdx.x * BR;
    const int col = wc * 16 + l15;

    // ---- stage A fragments: 2048 records, 2 per thread, contiguous writes ----
    #pragma unroll
    for (int i = 0; i < 2; ++i) {
        int rec = tid + i * 1024;             // 0..2047
        int ks = rec >> 6;
        int lr = rec & 63;
        int row = lr & 15;
        int lgr = lr >> 4;
        half8 h = (half8){0, 0, 0, 0, 0, 0, 0, 0};
        if (row < BR) {
            int d0 = ks * 16 + lgr * 4;
            float4 v = *reinterpret_cast<const float4*>(
                &x[(size_t)(b0 + row) * TD + d0]);
            h[0] = (_Float16)(v.x * v.x); h[1] = (_Float16)v.x;
            h[2] = (_Float16)(v.y * v.y); h[3] = (_Float16)v.y;
            h[4] = (_Float16)(v.z * v.z); h[5] = (_Float16)v.z;
            h[6] = (_Float16)(v.w * v.w); h[7] = (_Float16)v.w;
        }
        *reinterpret_cast<half8*>(&XAf[(size_t)rec * 8]) = h;
    }
    __syncthreads();

    // ---- GEMM: 16 MFMA per wave over this wave's K'-half ----
    const half8* wfp = reinterpret_cast<const half8*>(Wfrag)
                       + ((size_t)(wc * NKS + kh * 16) * 64 + l);
    const half8* xap = reinterpret_cast<const half8*>(XAf)
                       + ((size_t)(kh * 16) * 64 + l);
    f32x4 acc0 = (f32x4){0.f, 0.f, 0.f, 0.f};
    f32x4 acc1 = (f32x4){0.f, 0.f, 0.f, 0.f};
    #pragma unroll
    for (int i = 0; i < 16; i += 2) {
        half8 bv0 = wfp[(size_t)i * 64];
        half8 av0 = xap[(size_t)i * 64];
        half8 bv1 = wfp[(size_t)(i + 1) * 64];
        half8 av1 = xap[(size_t)(i + 1) * 64];
        acc0 = __builtin_amdgcn_mfma_f32_16x16x32_f16(av0, bv0, acc0, 0, 0, 0);
        acc1 = __builtin_amdgcn_mfma_f32_16x16x32_f16(av1, bv1, acc1, 0, 0, 0);
    }
    f32x4 acc = acc0 + acc1;

    // ---- combine the two K'-halves through LDS ----
    if (kh == 1) *reinterpret_cast<f32x4*>(&accX[wc][l][0]) = acc;
    __syncthreads();

    float sv[4];
    float bv[4], bg[4], ps[4];
    int bi[4];
    if (kh == 0) {
        acc += *reinterpret_cast<const f32x4*>(&accX[wc][l][0]);

        // ---- per-wave softmax partials over its 16 cols ----
        const float offc = off[col];
        #pragma unroll
        for (int e = 0; e < 4; ++e) {
            sv[e] = fmaf(-0.5f, acc[e], offc);
            bv[e] = sv[e]; bi[e] = col; bg[e] = acc[e];
        }
        #pragma unroll
        for (int msk = 1; msk <= 8; msk <<= 1) {
            #pragma unroll
            for (int e = 0; e < 4; ++e) {
                float ov = __shfl_xor(bv[e], msk, 64);
                int   oi = __shfl_xor(bi[e], msk, 64);
                float og = __shfl_xor(bg[e], msk, 64);
                if (ov > bv[e] || (ov == bv[e] && oi < bi[e])) {
                    bv[e] = ov; bi[e] = oi; bg[e] = og;
                }
            }
        }
        #pragma unroll
        for (int e = 0; e < 4; ++e) ps[e] = expf(sv[e] - bv[e]);
        #pragma unroll
        for (int msk = 1; msk <= 8; msk <<= 1)
            #pragma unroll
            for (int e = 0; e < 4; ++e) ps[e] += __shfl_xor(ps[e], msk, 64);

        if (l15 == 0) {
            #pragma unroll
            for (int e = 0; e < 4; ++e) {
                int r = lg * 4 + e;
                if (r < BR) {
                    red_m[wc][r] = bv[e];
                    red_s[wc][r] = ps[e];
                    red_i[wc][r] = bi[e];
                    red_g[wc][r] = bg[e];
                }
            }
        }
    }
    __syncthreads();

    if (kh == 0) {
        // ---- combine 8 col-groups -> lse ; write resp ----
        const float LOGC = -18.420680743952367f;  // ln(1e-8)
        #pragma unroll
        for (int e = 0; e < 4; ++e) {
            int r = lg * 4 + e;
            if (r < BR) {
                float M = red_m[0][r];
                #pragma unroll
                for (int w2 = 1; w2 < 8; ++w2) M = fmaxf(M, red_m[w2][r]);
                float S = 0.f;
                #pragma unroll
                for (int w2 = 0; w2 < 8; ++w2) S += red_s[w2][r] * expf(red_m[w2][r] - M);
                float lse = logf(S) + M;
                out[(size_t)(b0 + r) * TK + col] = fmaxf(sv[e] - lse, LOGC);
            }
        }

        // ---- dist: global argmax over col-groups, wave-0 leaders write ----
        if (wc == 0 && l15 == 0) {
            #pragma unroll
            for (int e = 0; e < 4; ++e) {
                int r = lg * 4 + e;
                if (r < BR) {
                    float v = red_m[0][r]; int ki = red_i[0][r]; float g = red_g[0][r];
                    #pragma unroll
                    for (int w2 = 1; w2 < 8; ++w2) {
                        float v2 = red_m[w2][r]; int i2 = red_i[w2][r];
                        if (v2 > v || (v2 == v && i2 < ki)) { v = v2; ki = i2; g = red_g[w2][r]; }
                    }
                    out[(size_t)TB * TK + b0 + r] = sqrtf(fmaxf(g + ebuf[ki], 0.f));
                }
            }
        }
    }
}

// ---------------------------------------------------------------------------
extern "C" void kernel_launch(void* const* d_in, const int* in_sizes, int n_in,
                              void* d_out, int out_size, void* d_ws, size_t ws_size,
                              hipStream_t stream) {
    const float* x  = (const float*)d_in[0];
    const float* C  = (const float*)d_in[1];
    const float* Dm = (const float*)d_in[2];
    float* out = (float*)d_out;

    _Float16* Wfrag = (_Float16*)d_ws;                                 // 256 KB
    float* off  = (float*)((char*)d_ws + (size_t)TK * 2 * TD * 2);     // 512 B
    float* ebuf = off + TK;                                            // 512 B

    prep_kernel<<<TK, 128, 0, stream>>>(C, Dm, Wfrag, off, ebuf);
    gmm_kernel<<<NBLK, 1024, 0, stream>>>(x, Wfrag, off, ebuf, out);
}

// Round 18
// 20.516 us; speedup vs baseline: 7.5412x; 1.0582x over previous
//
#include <hip/hip_runtime.h>
#include <math.h>

#define TB 2048
#define TK 128
#define TD 512
#define BR 4                 // real rows per block (MFMA M=16, rows 4..15 zero)
#define NBLK (TB / BR)       // 512 blocks = 2 per CU (phase overlap)
#define NKS 32               // K' = 1024 = 32 MFMA k-steps of 32

typedef _Float16 half8 __attribute__((ext_vector_type(8)));
typedef float f32x4 __attribute__((ext_vector_type(4)));

// k' mapping (both operands): k' = 2*d + t ; t=0 -> A:x^2, B:1/a ; t=1 -> A:x, B:-2c/a
// Fragment record (ks, lane): col/row = lane&15, d0 = ks*16 + (lane>>4)*4
// ws: Wfrag f16[8 cb][32 ks][64 lane][8] = 256 KB ; off f32[128] ; ebuf f32[128]

// ---------------------------------------------------------------------------
__global__ __launch_bounds__(128) void prep_kernel(const float* __restrict__ C,
        const float* __restrict__ Dm, _Float16* __restrict__ Wfrag,
        float* __restrict__ off, float* __restrict__ ebuf) {
    __shared__ float sE[2], sL[2];
    const int k = blockIdx.x;
    const int t = threadIdx.x;
    const int ks = t >> 2, lg = t & 3;
    const int d0 = ks * 16 + lg * 4;

    float4 dv = *reinterpret_cast<const float4*>(&Dm[(size_t)k * TD + d0]);
    float4 cv = *reinterpret_cast<const float4*>(&C[(size_t)k * TD + d0]);
    float a0 = fabsf(dv.x) + 1e-8f, a1 = fabsf(dv.y) + 1e-8f;
    float a2 = fabsf(dv.z) + 1e-8f, a3 = fabsf(dv.w) + 1e-8f;
    float i0 = 1.f / a0, i1 = 1.f / a1, i2 = 1.f / a2, i3 = 1.f / a3;
    float c0 = cv.x * i0, c1 = cv.y * i1, c2 = cv.z * i2, c3 = cv.w * i3;

    half8 h;
    h[0] = (_Float16)i0; h[1] = (_Float16)(-2.f * c0);
    h[2] = (_Float16)i1; h[3] = (_Float16)(-2.f * c1);
    h[4] = (_Float16)i2; h[5] = (_Float16)(-2.f * c2);
    h[6] = (_Float16)i3; h[7] = (_Float16)(-2.f * c3);
    *reinterpret_cast<half8*>(
        &Wfrag[(((size_t)(k >> 4) * NKS + ks) * 64 + lg * 16 + (k & 15)) * 8]) = h;

    float es = (cv.x * c0 + cv.y * c1) + (cv.z * c2 + cv.w * c3);
    float ls = logf((a0 * a1) * (a2 * a3));   // a in [0.9,1.1]: product safe
    #pragma unroll
    for (int m = 1; m <= 32; m <<= 1) {
        es += __shfl_xor(es, m, 64);
        ls += __shfl_xor(ls, m, 64);
    }
    if ((t & 63) == 0) { sE[t >> 6] = es; sL[t >> 6] = ls; }
    __syncthreads();
    if (t == 0) {
        float E = sE[0] + sE[1], L = sL[0] + sL[1];
        off[k] = -0.5f * (E + L);
        ebuf[k] = E;
    }
}

// ---------------------------------------------------------------------------
// main: 512 blocks x 1024 thr (16 waves) = 2 blocks/CU, 32 waves/CU (100%).
// Block = 4 rows x 128 cols, K' split across wave-halves: wave (kh, wc) does
// 16 MFMA of K'-half kh for col-group wc (16 cols). Epilogue: per-wave
// partials -> LDS; ONE kh=1 wave computes lse/argmax/dist; kh=0 waves write.
// ---------------------------------------------------------------------------
__global__ __launch_bounds__(1024) void gmm_kernel(const float* __restrict__ x,
        const _Float16* __restrict__ Wfrag, const float* __restrict__ off,
        const float* __restrict__ ebuf, float* __restrict__ out) {
    __shared__ __align__(16) _Float16 XAf[NKS * 64 * 8];   // 32 KB, fragment order
    __shared__ __align__(16) float accX[8][64][4];         // 8 KB
    __shared__ float red_m[8][BR], red_s[8][BR], red_g[8][BR];
    __shared__ int   red_i[8][BR];
    __shared__ float red_lse[BR];

    const int tid = threadIdx.x;
    const int l = tid & 63;
    const int w = tid >> 6;       // 0..15
    const int kh = w >> 3;        // K'-half
    const int wc = w & 7;         // col-group
    const int l15 = l & 15;
    const int lg = l >> 4;
    const int b0 = blockIdx.x * BR;
    const int col = wc * 16 + l15;

    // ---- stage A fragments: 2048 records, 2 per thread, contiguous writes ----
    #pragma unroll
    for (int i = 0; i < 2; ++i) {
        int rec = tid + i * 1024;             // 0..2047
        int ks = rec >> 6;
        int lr = rec & 63;
        int row = lr & 15;
        int lgr = lr >> 4;
        half8 h = (half8){0, 0, 0, 0, 0, 0, 0, 0};
        if (row < BR) {
            int d0 = ks * 16 + lgr * 4;
            float4 v = *reinterpret_cast<const float4*>(
                &x[(size_t)(b0 + row) * TD + d0]);
            h[0] = (_Float16)(v.x * v.x); h[1] = (_Float16)v.x;
            h[2] = (_Float16)(v.y * v.y); h[3] = (_Float16)v.y;
            h[4] = (_Float16)(v.z * v.z); h[5] = (_Float16)v.z;
            h[6] = (_Float16)(v.w * v.w); h[7] = (_Float16)v.w;
        }
        *reinterpret_cast<half8*>(&XAf[(size_t)rec * 8]) = h;
    }
    __syncthreads();

    // ---- GEMM: 16 MFMA per wave over this wave's K'-half ----
    const half8* wfp = reinterpret_cast<const half8*>(Wfrag)
                       + ((size_t)(wc * NKS + kh * 16) * 64 + l);
    const half8* xap = reinterpret_cast<const half8*>(XAf)
                       + ((size_t)(kh * 16) * 64 + l);
    f32x4 acc0 = (f32x4){0.f, 0.f, 0.f, 0.f};
    f32x4 acc1 = (f32x4){0.f, 0.f, 0.f, 0.f};
    #pragma unroll
    for (int i = 0; i < 16; i += 2) {
        half8 bv0 = wfp[(size_t)i * 64];
        half8 av0 = xap[(size_t)i * 64];
        half8 bv1 = wfp[(size_t)(i + 1) * 64];
        half8 av1 = xap[(size_t)(i + 1) * 64];
        acc0 = __builtin_amdgcn_mfma_f32_16x16x32_f16(av0, bv0, acc0, 0, 0, 0);
        acc1 = __builtin_amdgcn_mfma_f32_16x16x32_f16(av1, bv1, acc1, 0, 0, 0);
    }
    f32x4 acc = acc0 + acc1;

    // ---- combine the two K'-halves through LDS ----
    if (kh == 1) *reinterpret_cast<f32x4*>(&accX[wc][l][0]) = acc;
    __syncthreads();

    float sv[4];
    if (kh == 0) {
        acc += *reinterpret_cast<const f32x4*>(&accX[wc][l][0]);

        // ---- per-wave softmax partials over its 16 cols ----
        const float offc = off[col];
        float bv[4], bg[4], ps[4];
        int bi[4];
        #pragma unroll
        for (int e = 0; e < 4; ++e) {
            sv[e] = fmaf(-0.5f, acc[e], offc);
            bv[e] = sv[e]; bi[e] = col; bg[e] = acc[e];
        }
        #pragma unroll
        for (int msk = 1; msk <= 8; msk <<= 1) {
            #pragma unroll
            for (int e = 0; e < 4; ++e) {
                float ov = __shfl_xor(bv[e], msk, 64);
                int   oi = __shfl_xor(bi[e], msk, 64);
                float og = __shfl_xor(bg[e], msk, 64);
                if (ov > bv[e] || (ov == bv[e] && oi < bi[e])) {
                    bv[e] = ov; bi[e] = oi; bg[e] = og;
                }
            }
        }
        #pragma unroll
        for (int e = 0; e < 4; ++e) ps[e] = expf(sv[e] - bv[e]);
        #pragma unroll
        for (int msk = 1; msk <= 8; msk <<= 1)
            #pragma unroll
            for (int e = 0; e < 4; ++e) ps[e] += __shfl_xor(ps[e], msk, 64);

        // rows r = lg*4+e valid only for lg==0 (BR=4): lane 0 stores
        if (l == 0) {
            #pragma unroll
            for (int e = 0; e < 4; ++e) {
                red_m[wc][e] = bv[e];
                red_s[wc][e] = ps[e];
                red_i[wc][e] = bi[e];
                red_g[wc][e] = bg[e];
            }
        }
    }
    __syncthreads();

    // ---- single wave (kh=1, wc=0): per-row lse + argmax + dist ----
    if (w == 8 && l < BR) {
        const int r = l;
        float M = red_m[0][r];
        #pragma unroll
        for (int w2 = 1; w2 < 8; ++w2) M = fmaxf(M, red_m[w2][r]);
        float S = 0.f;
        #pragma unroll
        for (int w2 = 0; w2 < 8; ++w2) S += red_s[w2][r] * expf(red_m[w2][r] - M);
        red_lse[r] = logf(S) + M;

        float v = red_m[0][r]; int ki = red_i[0][r]; float g = red_g[0][r];
        #pragma unroll
        for (int w2 = 1; w2 < 8; ++w2) {
            float v2 = red_m[w2][r]; int i2 = red_i[w2][r];
            if (v2 > v || (v2 == v && i2 < ki)) { v = v2; ki = i2; g = red_g[w2][r]; }
        }
        out[(size_t)TB * TK + b0 + r] = sqrtf(fmaxf(g + ebuf[ki], 0.f));
    }
    __syncthreads();

    // ---- kh=0 waves, lanes lg==0: write resp rows 0..3 ----
    if (kh == 0 && lg == 0) {
        const float LOGC = -18.420680743952367f;  // ln(1e-8)
        #pragma unroll
        for (int e = 0; e < 4; ++e) {
            out[(size_t)(b0 + e) * TK + col] = fmaxf(sv[e] - red_lse[e], LOGC);
        }
    }
}

// ---------------------------------------------------------------------------
extern "C" void kernel_launch(void* const* d_in, const int* in_sizes, int n_in,
                              void* d_out, int out_size, void* d_ws, size_t ws_size,
                              hipStream_t stream) {
    const float* x  = (const float*)d_in[0];
    const float* C  = (const float*)d_in[1];
    const float* Dm = (const float*)d_in[2];
    float* out = (float*)d_out;

    _Float16* Wfrag = (_Float16*)d_ws;                                 // 256 KB
    float* off  = (float*)((char*)d_ws + (size_t)TK * 2 * TD * 2);     // 512 B
    float* ebuf = off + TK;                                            // 512 B

    prep_kernel<<<TK, 128, 0, stream>>>(C, Dm, Wfrag, off, ebuf);
    gmm_kernel<<<NBLK, 1024, 0, stream>>>(x, Wfrag, off, ebuf, out);
}

// Round 19
// 19.689 us; speedup vs baseline: 7.8577x; 1.0420x over previous
//
#include <hip/hip_runtime.h>
#include <math.h>

#define TB 2048
#define TK 128
#define TD 512
#define BR 8                 // real rows per block/tile (MFMA M=16, rows 8..15 zero)
#define NTILE (TB / BR)      // 256 row-tiles
#define NKS 32               // K' = 1024 = 32 MFMA k-steps of 32

typedef _Float16 half8 __attribute__((ext_vector_type(8)));
typedef float f32x4 __attribute__((ext_vector_type(4)));

// k' mapping (both operands): k' = 2*d + t ; t=0 -> A:x^2, B:1/a ; t=1 -> A:x, B:-2c/a
// Fragment record (ks, lane): row/col = lane&15, d0 = ks*16 + (lane>>4)*4
// ws: Wfrag f16[8 cb][32 ks][64][8] = 256 KB ; off f32[128] ; ebuf f32[128] ;
//     XF f16[256 tile][32 ks][64][8] = 8 MB  (A-fragments, rows 8..15 zero)

// ---------------------------------------------------------------------------
// prep: blocks 0..127 build B-fragments + off/ebuf for class k = bid.
//       blocks 128..383 build A-fragments for row-tile bid-128.
// ---------------------------------------------------------------------------
__global__ __launch_bounds__(128) void prep_kernel(const float* __restrict__ x,
        const float* __restrict__ C, const float* __restrict__ Dm,
        _Float16* __restrict__ Wfrag, _Float16* __restrict__ XF,
        float* __restrict__ off, float* __restrict__ ebuf) {
    __shared__ float sE[2], sL[2];
    const int bid = blockIdx.x;
    const int t = threadIdx.x;

    if (bid < TK) {
        const int k = bid;
        const int ks = t >> 2, lg = t & 3;
        const int d0 = ks * 16 + lg * 4;

        float4 dv = *reinterpret_cast<const float4*>(&Dm[(size_t)k * TD + d0]);
        float4 cv = *reinterpret_cast<const float4*>(&C[(size_t)k * TD + d0]);
        float a0 = fabsf(dv.x) + 1e-8f, a1 = fabsf(dv.y) + 1e-8f;
        float a2 = fabsf(dv.z) + 1e-8f, a3 = fabsf(dv.w) + 1e-8f;
        float i0 = 1.f / a0, i1 = 1.f / a1, i2 = 1.f / a2, i3 = 1.f / a3;
        float c0 = cv.x * i0, c1 = cv.y * i1, c2 = cv.z * i2, c3 = cv.w * i3;

        half8 h;
        h[0] = (_Float16)i0; h[1] = (_Float16)(-2.f * c0);
        h[2] = (_Float16)i1; h[3] = (_Float16)(-2.f * c1);
        h[4] = (_Float16)i2; h[5] = (_Float16)(-2.f * c2);
        h[6] = (_Float16)i3; h[7] = (_Float16)(-2.f * c3);
        *reinterpret_cast<half8*>(
            &Wfrag[(((size_t)(k >> 4) * NKS + ks) * 64 + lg * 16 + (k & 15)) * 8]) = h;

        float es = (cv.x * c0 + cv.y * c1) + (cv.z * c2 + cv.w * c3);
        float ls = logf((a0 * a1) * (a2 * a3));   // a in [0.9,1.1]: product safe
        #pragma unroll
        for (int m = 1; m <= 32; m <<= 1) {
            es += __shfl_xor(es, m, 64);
            ls += __shfl_xor(ls, m, 64);
        }
        if ((t & 63) == 0) { sE[t >> 6] = es; sL[t >> 6] = ls; }
        __syncthreads();
        if (t == 0) {
            float E = sE[0] + sE[1], L = sL[0] + sL[1];
            off[k] = -0.5f * (E + L);
            ebuf[k] = E;
        }
    } else {
        const int tile = bid - TK;
        const int b0 = tile * BR;
        #pragma unroll
        for (int i = 0; i < 16; ++i) {
            int rec = t + i * 128;            // 0..2047
            int ks = rec >> 6;
            int ln = rec & 63;
            int row = ln & 15;
            int lgr = ln >> 4;
            half8 h = (half8){0, 0, 0, 0, 0, 0, 0, 0};
            if (row < BR) {
                int d0 = ks * 16 + lgr * 4;
                float4 v = *reinterpret_cast<const float4*>(
                    &x[(size_t)(b0 + row) * TD + d0]);
                h[0] = (_Float16)(v.x * v.x); h[1] = (_Float16)v.x;
                h[2] = (_Float16)(v.y * v.y); h[3] = (_Float16)v.y;
                h[4] = (_Float16)(v.z * v.z); h[5] = (_Float16)v.z;
                h[6] = (_Float16)(v.w * v.w); h[7] = (_Float16)v.w;
            }
            *reinterpret_cast<half8*>(
                &XF[((size_t)(tile * NKS + ks) * 64 + ln) * 8]) = h;
        }
    }
}

// ---------------------------------------------------------------------------
// main: 256 blocks x 1024 thr (16 waves) = 2 blocks/CU, 32 waves/CU.
// Pure streaming GEMM: wave (kh, wc) does 16 MFMA of K'-half kh for col-group
// wc; A and B fragments both read directly from global (L2-resident, 1 KB
// contiguous per wave-load). No LDS staging, no pre-MFMA barrier.
// ---------------------------------------------------------------------------
__global__ __launch_bounds__(1024, 2) void gmm_kernel(
        const _Float16* __restrict__ XF, const _Float16* __restrict__ Wfrag,
        const float* __restrict__ off, const float* __restrict__ ebuf,
        float* __restrict__ out) {
    __shared__ __align__(16) float accX[8][64][4];         // 8 KB
    __shared__ float red_m[8][BR], red_s[8][BR], red_g[8][BR];
    __shared__ int   red_i[8][BR];
    __shared__ float red_lse[BR];

    const int tid = threadIdx.x;
    const int l = tid & 63;
    const int w = tid >> 6;       // 0..15
    const int kh = w >> 3;        // K'-half
    const int wc = w & 7;         // col-group
    const int l15 = l & 15;
    const int lg = l >> 4;
    const int b0 = blockIdx.x * BR;
    const int col = wc * 16 + l15;

    const half8* ap = reinterpret_cast<const half8*>(XF)
                      + ((size_t)(blockIdx.x * NKS + kh * 16) * 64 + l);
    const half8* bp = reinterpret_cast<const half8*>(Wfrag)
                      + ((size_t)(wc * NKS + kh * 16) * 64 + l);

    f32x4 acc0 = (f32x4){0.f, 0.f, 0.f, 0.f};
    f32x4 acc1 = (f32x4){0.f, 0.f, 0.f, 0.f};
    #pragma unroll
    for (int i = 0; i < 16; i += 2) {
        half8 av0 = ap[(size_t)i * 64];
        half8 bv0 = bp[(size_t)i * 64];
        half8 av1 = ap[(size_t)(i + 1) * 64];
        half8 bv1 = bp[(size_t)(i + 1) * 64];
        acc0 = __builtin_amdgcn_mfma_f32_16x16x32_f16(av0, bv0, acc0, 0, 0, 0);
        acc1 = __builtin_amdgcn_mfma_f32_16x16x32_f16(av1, bv1, acc1, 0, 0, 0);
    }
    f32x4 acc = acc0 + acc1;

    // ---- combine the two K'-halves through LDS ----
    if (kh == 1) *reinterpret_cast<f32x4*>(&accX[wc][l][0]) = acc;
    __syncthreads();

    float sv[4];
    if (kh == 0) {
        acc += *reinterpret_cast<const f32x4*>(&accX[wc][l][0]);

        // ---- per-wave softmax partials over its 16 cols ----
        const float offc = off[col];
        float bv[4], bg[4], ps[4];
        int bi[4];
        #pragma unroll
        for (int e = 0; e < 4; ++e) {
            sv[e] = fmaf(-0.5f, acc[e], offc);
            bv[e] = sv[e]; bi[e] = col; bg[e] = acc[e];
        }
        #pragma unroll
        for (int msk = 1; msk <= 8; msk <<= 1) {
            #pragma unroll
            for (int e = 0; e < 4; ++e) {
                float ov = __shfl_xor(bv[e], msk, 64);
                int   oi = __shfl_xor(bi[e], msk, 64);
                float og = __shfl_xor(bg[e], msk, 64);
                if (ov > bv[e] || (ov == bv[e] && oi < bi[e])) {
                    bv[e] = ov; bi[e] = oi; bg[e] = og;
                }
            }
        }
        #pragma unroll
        for (int e = 0; e < 4; ++e) ps[e] = expf(sv[e] - bv[e]);
        #pragma unroll
        for (int msk = 1; msk <= 8; msk <<= 1)
            #pragma unroll
            for (int e = 0; e < 4; ++e) ps[e] += __shfl_xor(ps[e], msk, 64);

        // rows r = lg*4+e valid for lg < 2 (BR=8)
        if (l15 == 0 && lg < 2) {
            #pragma unroll
            for (int e = 0; e < 4; ++e) {
                int r = lg * 4 + e;
                red_m[wc][r] = bv[e];
                red_s[wc][r] = ps[e];
                red_i[wc][r] = bi[e];
                red_g[wc][r] = bg[e];
            }
        }
    }
    __syncthreads();

    // ---- single wave (kh=1, wc=0): per-row lse + argmax + dist ----
    if (w == 8 && l < BR) {
        const int r = l;
        float M = red_m[0][r];
        #pragma unroll
        for (int w2 = 1; w2 < 8; ++w2) M = fmaxf(M, red_m[w2][r]);
        float S = 0.f;
        #pragma unroll
        for (int w2 = 0; w2 < 8; ++w2) S += red_s[w2][r] * expf(red_m[w2][r] - M);
        red_lse[r] = logf(S) + M;

        float v = red_m[0][r]; int ki = red_i[0][r]; float g = red_g[0][r];
        #pragma unroll
        for (int w2 = 1; w2 < 8; ++w2) {
            float v2 = red_m[w2][r]; int i2 = red_i[w2][r];
            if (v2 > v || (v2 == v && i2 < ki)) { v = v2; ki = i2; g = red_g[w2][r]; }
        }
        out[(size_t)TB * TK + b0 + r] = sqrtf(fmaxf(g + ebuf[ki], 0.f));
    }
    __syncthreads();

    // ---- kh=0 waves, lanes lg<2: write resp rows 0..7 ----
    if (kh == 0 && lg < 2) {
        const float LOGC = -18.420680743952367f;  // ln(1e-8)
        #pragma unroll
        for (int e = 0; e < 4; ++e) {
            int r = lg * 4 + e;
            out[(size_t)(b0 + r) * TK + col] = fmaxf(sv[e] - red_lse[r], LOGC);
        }
    }
}

// ---------------------------------------------------------------------------
extern "C" void kernel_launch(void* const* d_in, const int* in_sizes, int n_in,
                              void* d_out, int out_size, void* d_ws, size_t ws_size,
                              hipStream_t stream) {
    const float* x  = (const float*)d_in[0];
    const float* C  = (const float*)d_in[1];
    const float* Dm = (const float*)d_in[2];
    float* out = (float*)d_out;

    _Float16* Wfrag = (_Float16*)d_ws;                                 // 256 KB
    float* off  = (float*)((char*)d_ws + (size_t)TK * 2 * TD * 2);     // 512 B
    float* ebuf = off + TK;                                            // 512 B
    _Float16* XF = (_Float16*)((char*)d_ws + (1 << 20));               // 8 MB

    prep_kernel<<<TK + NTILE, 128, 0, stream>>>(x, C, Dm, Wfrag, XF, off, ebuf);
    gmm_kernel<<<NTILE, 1024, 0, stream>>>(XF, Wfrag, off, ebuf, out);
}

// Round 20
// 19.287 us; speedup vs baseline: 8.0217x; 1.0209x over previous
//
#include <hip/hip_runtime.h>
#include <math.h>

#define TB 2048
#define TK 128
#define TD 512
#define BR 8                 // real rows per block/tile (MFMA M=16, rows 8..15 zero)
#define NTILE (TB / BR)      // 256 row-tiles
#define NKS 32               // K' = 1024 = 32 MFMA k-steps of 32

typedef _Float16 half8 __attribute__((ext_vector_type(8)));
typedef float f32x4 __attribute__((ext_vector_type(4)));

// k' mapping (both operands): k' = 2*d + t ; t=0 -> A:x^2, B:1/a ; t=1 -> A:x, B:-2c/a
// Fragment record (ks, lane): row/col = lane&15, d0 = ks*16 + (lane>>4)*4
// ws: Wfrag f16[8 cb][32 ks][64][8] = 256 KB ; off f32[128] ; ebuf f32[128] ;
//     XF f16[256 tile][32 ks][64][8] = 8 MB  (A-fragments, rows 8..15 zero)

// ---------------------------------------------------------------------------
// prep: blocks 0..127 build B-fragments + off/ebuf for class k = bid.
//       blocks 128..383 build A-fragments for row-tile bid-128.
// ---------------------------------------------------------------------------
__global__ __launch_bounds__(128) void prep_kernel(const float* __restrict__ x,
        const float* __restrict__ C, const float* __restrict__ Dm,
        _Float16* __restrict__ Wfrag, _Float16* __restrict__ XF,
        float* __restrict__ off, float* __restrict__ ebuf) {
    __shared__ float sE[2], sL[2];
    const int bid = blockIdx.x;
    const int t = threadIdx.x;

    if (bid < TK) {
        const int k = bid;
        const int ks = t >> 2, lg = t & 3;
        const int d0 = ks * 16 + lg * 4;

        float4 dv = *reinterpret_cast<const float4*>(&Dm[(size_t)k * TD + d0]);
        float4 cv = *reinterpret_cast<const float4*>(&C[(size_t)k * TD + d0]);
        float a0 = fabsf(dv.x) + 1e-8f, a1 = fabsf(dv.y) + 1e-8f;
        float a2 = fabsf(dv.z) + 1e-8f, a3 = fabsf(dv.w) + 1e-8f;
        float i0 = 1.f / a0, i1 = 1.f / a1, i2 = 1.f / a2, i3 = 1.f / a3;
        float c0 = cv.x * i0, c1 = cv.y * i1, c2 = cv.z * i2, c3 = cv.w * i3;

        half8 h;
        h[0] = (_Float16)i0; h[1] = (_Float16)(-2.f * c0);
        h[2] = (_Float16)i1; h[3] = (_Float16)(-2.f * c1);
        h[4] = (_Float16)i2; h[5] = (_Float16)(-2.f * c2);
        h[6] = (_Float16)i3; h[7] = (_Float16)(-2.f * c3);
        *reinterpret_cast<half8*>(
            &Wfrag[(((size_t)(k >> 4) * NKS + ks) * 64 + lg * 16 + (k & 15)) * 8]) = h;

        float es = (cv.x * c0 + cv.y * c1) + (cv.z * c2 + cv.w * c3);
        float ls = logf((a0 * a1) * (a2 * a3));   // a in [0.9,1.1]: product safe
        #pragma unroll
        for (int m = 1; m <= 32; m <<= 1) {
            es += __shfl_xor(es, m, 64);
            ls += __shfl_xor(ls, m, 64);
        }
        if ((t & 63) == 0) { sE[t >> 6] = es; sL[t >> 6] = ls; }
        __syncthreads();
        if (t == 0) {
            float E = sE[0] + sE[1], L = sL[0] + sL[1];
            off[k] = -0.5f * (E + L);
            ebuf[k] = E;
        }
    } else {
        const int tile = bid - TK;
        const int b0 = tile * BR;
        #pragma unroll
        for (int i = 0; i < 16; ++i) {
            int rec = t + i * 128;            // 0..2047
            int ks = rec >> 6;
            int ln = rec & 63;
            int row = ln & 15;
            int lgr = ln >> 4;
            half8 h = (half8){0, 0, 0, 0, 0, 0, 0, 0};
            if (row < BR) {
                int d0 = ks * 16 + lgr * 4;
                float4 v = *reinterpret_cast<const float4*>(
                    &x[(size_t)(b0 + row) * TD + d0]);
                h[0] = (_Float16)(v.x * v.x); h[1] = (_Float16)v.x;
                h[2] = (_Float16)(v.y * v.y); h[3] = (_Float16)v.y;
                h[4] = (_Float16)(v.z * v.z); h[5] = (_Float16)v.z;
                h[6] = (_Float16)(v.w * v.w); h[7] = (_Float16)v.w;
            }
            *reinterpret_cast<half8*>(
                &XF[((size_t)(tile * NKS + ks) * 64 + ln) * 8]) = h;
        }
    }
}

// ---------------------------------------------------------------------------
// main: 256 blocks x 512 thr (8 waves) = 2 blocks/CU, 4 waves/SIMD, 128 VGPR.
// Wave w owns cols [w*16, w*16+16) over the FULL K' (32 MFMA, 4 acc chains).
// A and B fragments streamed from global (L2-resident, contiguous 1 KB/wave
// load); 128-VGPR budget lets the compiler keep many loads in flight.
// ---------------------------------------------------------------------------
__global__ __launch_bounds__(512, 2) void gmm_kernel(
        const _Float16* __restrict__ XF, const _Float16* __restrict__ Wfrag,
        const float* __restrict__ off, const float* __restrict__ ebuf,
        float* __restrict__ out) {
    __shared__ float red_m[8][BR], red_s[8][BR], red_g[8][BR];
    __shared__ int   red_i[8][BR];
    __shared__ float red_lse[BR];

    const int tid = threadIdx.x;
    const int l = tid & 63;
    const int w = tid >> 6;       // 0..7 col-group
    const int l15 = l & 15;
    const int lg = l >> 4;
    const int b0 = blockIdx.x * BR;
    const int col = w * 16 + l15;

    const half8* ap = reinterpret_cast<const half8*>(XF)
                      + ((size_t)blockIdx.x * NKS * 64 + l);
    const half8* bp = reinterpret_cast<const half8*>(Wfrag)
                      + ((size_t)w * NKS * 64 + l);

    f32x4 acc0 = (f32x4){0.f, 0.f, 0.f, 0.f};
    f32x4 acc1 = (f32x4){0.f, 0.f, 0.f, 0.f};
    f32x4 acc2 = (f32x4){0.f, 0.f, 0.f, 0.f};
    f32x4 acc3 = (f32x4){0.f, 0.f, 0.f, 0.f};
    #pragma unroll
    for (int i = 0; i < NKS; i += 4) {
        half8 a0 = ap[(size_t)(i + 0) * 64];
        half8 q0 = bp[(size_t)(i + 0) * 64];
        half8 a1 = ap[(size_t)(i + 1) * 64];
        half8 q1 = bp[(size_t)(i + 1) * 64];
        half8 a2 = ap[(size_t)(i + 2) * 64];
        half8 q2 = bp[(size_t)(i + 2) * 64];
        half8 a3 = ap[(size_t)(i + 3) * 64];
        half8 q3 = bp[(size_t)(i + 3) * 64];
        acc0 = __builtin_amdgcn_mfma_f32_16x16x32_f16(a0, q0, acc0, 0, 0, 0);
        acc1 = __builtin_amdgcn_mfma_f32_16x16x32_f16(a1, q1, acc1, 0, 0, 0);
        acc2 = __builtin_amdgcn_mfma_f32_16x16x32_f16(a2, q2, acc2, 0, 0, 0);
        acc3 = __builtin_amdgcn_mfma_f32_16x16x32_f16(a3, q3, acc3, 0, 0, 0);
    }
    f32x4 acc = (acc0 + acc1) + (acc2 + acc3);

    // ---- per-wave softmax partials over its 16 cols ----
    const float offc = off[col];
    float sv[4], bv[4], bg[4], ps[4];
    int bi[4];
    #pragma unroll
    for (int e = 0; e < 4; ++e) {
        sv[e] = fmaf(-0.5f, acc[e], offc);
        bv[e] = sv[e]; bi[e] = col; bg[e] = acc[e];
    }
    #pragma unroll
    for (int msk = 1; msk <= 8; msk <<= 1) {
        #pragma unroll
        for (int e = 0; e < 4; ++e) {
            float ov = __shfl_xor(bv[e], msk, 64);
            int   oi = __shfl_xor(bi[e], msk, 64);
            float og = __shfl_xor(bg[e], msk, 64);
            if (ov > bv[e] || (ov == bv[e] && oi < bi[e])) {
                bv[e] = ov; bi[e] = oi; bg[e] = og;
            }
        }
    }
    #pragma unroll
    for (int e = 0; e < 4; ++e) ps[e] = expf(sv[e] - bv[e]);
    #pragma unroll
    for (int msk = 1; msk <= 8; msk <<= 1)
        #pragma unroll
        for (int e = 0; e < 4; ++e) ps[e] += __shfl_xor(ps[e], msk, 64);

    // rows r = lg*4+e valid for lg < 2 (BR=8)
    if (l15 == 0 && lg < 2) {
        #pragma unroll
        for (int e = 0; e < 4; ++e) {
            int r = lg * 4 + e;
            red_m[w][r] = bv[e];
            red_s[w][r] = ps[e];
            red_i[w][r] = bi[e];
            red_g[w][r] = bg[e];
        }
    }
    __syncthreads();

    // ---- one wave (w=7): per-row lse + argmax + dist ----
    if (w == 7 && l < BR) {
        const int r = l;
        float M = red_m[0][r];
        #pragma unroll
        for (int w2 = 1; w2 < 8; ++w2) M = fmaxf(M, red_m[w2][r]);
        float S = 0.f;
        #pragma unroll
        for (int w2 = 0; w2 < 8; ++w2) S += red_s[w2][r] * expf(red_m[w2][r] - M);
        red_lse[r] = logf(S) + M;

        float v = red_m[0][r]; int ki = red_i[0][r]; float g = red_g[0][r];
        #pragma unroll
        for (int w2 = 1; w2 < 8; ++w2) {
            float v2 = red_m[w2][r]; int i2 = red_i[w2][r];
            if (v2 > v || (v2 == v && i2 < ki)) { v = v2; ki = i2; g = red_g[w2][r]; }
        }
        out[(size_t)TB * TK + b0 + r] = sqrtf(fmaxf(g + ebuf[ki], 0.f));
    }
    __syncthreads();

    // ---- all waves, lanes lg<2: write resp rows 0..7 for col ----
    if (lg < 2) {
        const float LOGC = -18.420680743952367f;  // ln(1e-8)
        #pragma unroll
        for (int e = 0; e < 4; ++e) {
            int r = lg * 4 + e;
            out[(size_t)(b0 + r) * TK + col] = fmaxf(sv[e] - red_lse[r], LOGC);
        }
    }
}

// ---------------------------------------------------------------------------
extern "C" void kernel_launch(void* const* d_in, const int* in_sizes, int n_in,
                              void* d_out, int out_size, void* d_ws, size_t ws_size,
                              hipStream_t stream) {
    const float* x  = (const float*)d_in[0];
    const float* C  = (const float*)d_in[1];
    const float* Dm = (const float*)d_in[2];
    float* out = (float*)d_out;

    _Float16* Wfrag = (_Float16*)d_ws;                                 // 256 KB
    float* off  = (float*)((char*)d_ws + (size_t)TK * 2 * TD * 2);     // 512 B
    float* ebuf = off + TK;                                            // 512 B
    _Float16* XF = (_Float16*)((char*)d_ws + (1 << 20));               // 8 MB

    prep_kernel<<<TK + NTILE, 128, 0, stream>>>(x, C, Dm, Wfrag, XF, off, ebuf);
    gmm_kernel<<<NTILE, 512, 0, stream>>>(XF, Wfrag, off, ebuf, out);
}